// Round 9
// baseline (1028.434 us; speedup 1.0000x reference)
//
#include <hip/hip_runtime.h>
#include <stdint.h>

// PyramidGrid (instant-NGP hash grid, simplex interp) forward — R9.
//
// R8: gather8 = 81% of time at 0.37 lane-gathers/cyc/CU, 1.3TB/s HBM (16%),
// FETCH 368MB (L2 captures 91% of gather traffic) -> not traffic-bound any
// more; gather service rate is. R9: persistent gather — 1024 co-resident
// blocks, each loops the 8 levels internally (level-phasing preserved: all
// blocks sweep levels in the same order; run-ahead blocks self-throttle on
// cold lines). 8 points/thread per level -> 32 gathers in one fenced window
// (~2x in-flight), long-lived blocks (no redispatch).

constexpr uint32_t kBatch  = 1u << 21;
constexpr uint32_t kGBlks  = 1024u;                 // persistent gather grid
constexpr uint32_t kThr    = 256u;
constexpr uint32_t kStride = kGBlks * kThr;         // 262144 threads
constexpr size_t   kSlab   = (size_t)kBatch * 2u;   // floats per level slab

typedef float f32x2 __attribute__((ext_vector_type(2)));
typedef float f32x4 __attribute__((ext_vector_type(4)));

// cumulative row offsets (prev) and pow2 hash masks per level
__constant__ constexpr uint32_t PREV[16] = {
    0u, 4096u, 36864u, 299008u, 823296u, 1347584u, 1871872u, 2396160u,
    2920448u, 3444736u, 3969024u, 4493312u, 5017600u, 5541888u, 6066176u, 6590464u};
__constant__ constexpr uint32_t MASK[16] = {
    4095u, 32767u, 262143u, 524287u, 524287u, 524287u, 524287u, 524287u,
    524287u, 524287u, 524287u, 524287u, 524287u, 524287u, 524287u, 524287u};

// Shared per-point math (verified bit-exact vs reference in R1-R8).
__device__ __forceinline__ void corner_hashes_weights(
    float x0, float x1, float x2, float res, uint32_t mask, uint32_t prev,
    uint32_t& g0, uint32_t& g1, uint32_t& g2, uint32_t& g3,
    float& sa, float& sb, float& sc)
{
    const float fx0 = x0 * res;
    const float fx1 = x1 * res;
    const float fx2 = x2 * res;
    const int i0 = (int)fx0;            // trunc == floor (x >= 0)
    const int i1 = (int)fx1;
    const int i2 = (int)fx2;
    const float f0 = fx0 - (float)i0;   // exact fp32
    const float f1 = fx1 - (float)i1;
    const float f2 = fx2 - (float)i2;

    // stable ascending ranks (== inv_inds of stable argsort)
    const int r0 = (int)(f1 < f0) + (int)(f2 < f0);
    const int r1 = (int)(f0 < f1) + (int)(f2 < f1) + (int)(f0 == f1);
    const int r2 = (int)(f0 < f2) + (int)(f1 < f2) + (int)(f0 == f2) + (int)(f1 == f2);

    sa = fminf(fminf(f0, f1), f2);
    sc = fmaxf(fmaxf(f0, f1), f2);
    sb = __builtin_amdgcn_fmed3f(f0, f1, f2);

    // hash components (uint32 wrap multiply; PRIMES = {1, 2654435761, 805459861})
    const uint32_t A0 = (uint32_t)i0;
    const uint32_t A1 = A0 + 1u;
    const uint32_t B0 = (uint32_t)i1 * 2654435761u;
    const uint32_t B1 = ((uint32_t)i1 + 1u) * 2654435761u;
    const uint32_t C0 = (uint32_t)i2 * 805459861u;
    const uint32_t C1 = ((uint32_t)i2 + 1u) * 805459861u;

    const uint32_t h0 = A1 ^ B1 ^ C1;
    const uint32_t h1 = (r0 >= 1 ? A1 : A0) ^ (r1 >= 1 ? B1 : B0) ^ (r2 >= 1 ? C1 : C0);
    const uint32_t h2 = (r0 >= 2 ? A1 : A0) ^ (r1 >= 2 ? B1 : B0) ^ (r2 >= 2 ? C1 : C0);
    const uint32_t h3 = A0 ^ B0 ^ C0;

    g0 = (h0 & mask) + prev;
    g1 = (h1 & mask) + prev;
    g2 = (h2 & mask) + prev;
    g3 = (h3 & mask) + prev;
}

// ---------------- Persistent per-level gather: 8 levels per launch ----------
// 1024 blocks (co-resident at 4 waves/EU); each block sweeps levels base..base+7,
// processing all 2^21 points per level, 8 points/thread, 32 gathers in flight.

__global__ __launch_bounds__(256, 4) void gather8(
    const float* __restrict__ in,    // [B,3]
    const float* __restrict__ emb,   // [7114752,2]
    float* __restrict__ scr,         // [8][B][2]
    uint32_t base)                   // 0 or 8
{
    const uint32_t tid = blockIdx.x * kThr + threadIdx.x;   // 0..262143

#pragma unroll 1
    for (uint32_t l8 = 0u; l8 < 8u; ++l8) {
        const uint32_t lvl = base + l8;
        const float res = (float)(16u << lvl);
        const uint32_t mask = MASK[lvl];
        const uint32_t prev = PREV[lvl];
        float* slab = scr + (size_t)l8 * kSlab;

        f32x2 e[8][4];                  // 32 gather results (64 VGPRs)
        float sa[8], sb[8], sc[8];

        // Phase A: 8 points/thread -> issue all 32 gathers.
#pragma unroll
        for (int k = 0; k < 8; ++k) {
            const uint32_t b = tid + (uint32_t)k * kStride;
            const float x0 = __builtin_nontemporal_load(in + 3u * b + 0u);
            const float x1 = __builtin_nontemporal_load(in + 3u * b + 1u);
            const float x2 = __builtin_nontemporal_load(in + 3u * b + 2u);
            uint32_t g0, g1, g2, g3;
            corner_hashes_weights(x0, x1, x2, res, mask, prev, g0, g1, g2, g3,
                                  sa[k], sb[k], sc[k]);
            e[k][0] = *reinterpret_cast<const f32x2*>(emb + 2u * g0);
            e[k][1] = *reinterpret_cast<const f32x2*>(emb + 2u * g1);
            e[k][2] = *reinterpret_cast<const f32x2*>(emb + 2u * g2);
            e[k][3] = *reinterpret_cast<const f32x2*>(emb + 2u * g3);
        }

        // Data-dependency fence (R6-proven): all 32 loads materialize before
        // any consume -> max in-flight window.
        asm volatile(""
            : "+v"(e[0][0]), "+v"(e[0][1]), "+v"(e[0][2]), "+v"(e[0][3]),
              "+v"(e[1][0]), "+v"(e[1][1]), "+v"(e[1][2]), "+v"(e[1][3]),
              "+v"(e[2][0]), "+v"(e[2][1]), "+v"(e[2][2]), "+v"(e[2][3]),
              "+v"(e[3][0]), "+v"(e[3][1]), "+v"(e[3][2]), "+v"(e[3][3]));
        asm volatile(""
            : "+v"(e[4][0]), "+v"(e[4][1]), "+v"(e[4][2]), "+v"(e[4][3]),
              "+v"(e[5][0]), "+v"(e[5][1]), "+v"(e[5][2]), "+v"(e[5][3]),
              "+v"(e[6][0]), "+v"(e[6][1]), "+v"(e[6][2]), "+v"(e[6][3]),
              "+v"(e[7][0]), "+v"(e[7][1]), "+v"(e[7][2]), "+v"(e[7][3]));

        // Phase B: combine + coalesced 8B/lane NT stores.
#pragma unroll
        for (int k = 0; k < 8; ++k) {
            const float w0 = sa[k];
            const float w1 = sb[k] - sa[k];
            const float w2 = sc[k] - sb[k];
            const float w3 = 1.0f - sc[k];
            f32x2 v;
            v.x = w0 * e[k][0].x + w1 * e[k][1].x + w2 * e[k][2].x + w3 * e[k][3].x;
            v.y = w0 * e[k][0].y + w1 * e[k][1].y + w2 * e[k][2].y + w3 * e[k][3].y;
            const uint32_t b = tid + (uint32_t)k * kStride;
            __builtin_nontemporal_store(v, reinterpret_cast<f32x2*>(slab + 2u * (size_t)b));
        }
    }
}

// Assemble 8 level slabs -> contiguous 64B (one full line) per point.
__global__ __launch_bounds__(256) void transpose8(
    const float* __restrict__ scr,   // [8][B][2]
    float* __restrict__ out,         // [B,32]
    uint32_t half)                   // 0: levels 0-7, 1: levels 8-15
{
    const uint32_t b = blockIdx.x * 256u + threadIdx.x;
    float v[16];
#pragma unroll
    for (int l = 0; l < 8; ++l) {
        const f32x2 e = __builtin_nontemporal_load(
            reinterpret_cast<const f32x2*>(scr + (size_t)l * kSlab + 2u * (size_t)b));
        v[2 * l + 0] = e.x;
        v[2 * l + 1] = e.y;
    }
    float* o = out + (size_t)b * 32u + (size_t)half * 16u;
#pragma unroll
    for (int q = 0; q < 4; ++q) {
        f32x4 t;
        t.x = v[4 * q + 0];
        t.y = v[4 * q + 1];
        t.z = v[4 * q + 2];
        t.w = v[4 * q + 3];
        *reinterpret_cast<f32x4*>(o + 4 * q) = t;
    }
}

// ---------------- Fallback: monolithic (if ws too small) ----------------

__global__ __launch_bounds__(256) void pyramid_fwd_mono(
    const float* __restrict__ in,
    const float* __restrict__ emb,
    float* __restrict__ out)
{
    const uint32_t b = blockIdx.x * 256u + threadIdx.x;
    const float x0 = in[3u * b + 0u];
    const float x1 = in[3u * b + 1u];
    const float x2 = in[3u * b + 2u];

#pragma unroll
    for (int g = 0; g < 2; ++g) {
        float o8[16];
#pragma unroll
        for (int k = 0; k < 8; ++k) {
            const int lvl = g * 8 + k;
            const float res = (float)(16 << lvl);
            uint32_t g0, g1, g2, g3;
            float sa, sb, sc;
            corner_hashes_weights(x0, x1, x2, res, MASK[lvl], PREV[lvl],
                                  g0, g1, g2, g3, sa, sb, sc);
            const f32x2 e0 = *reinterpret_cast<const f32x2*>(emb + 2u * g0);
            const f32x2 e1 = *reinterpret_cast<const f32x2*>(emb + 2u * g1);
            const f32x2 e2 = *reinterpret_cast<const f32x2*>(emb + 2u * g2);
            const f32x2 e3 = *reinterpret_cast<const f32x2*>(emb + 2u * g3);
            const float w0 = sa, w1 = sb - sa, w2 = sc - sb, w3 = 1.0f - sc;
            o8[2 * k + 0] = w0 * e0.x + w1 * e1.x + w2 * e2.x + w3 * e3.x;
            o8[2 * k + 1] = w0 * e0.y + w1 * e1.y + w2 * e2.y + w3 * e3.y;
        }
        f32x4* o = reinterpret_cast<f32x4*>(out + (size_t)b * 32u + (size_t)g * 16u);
#pragma unroll
        for (int q = 0; q < 4; ++q) {
            f32x4 v;
            v.x = o8[4 * q + 0];
            v.y = o8[4 * q + 1];
            v.z = o8[4 * q + 2];
            v.w = o8[4 * q + 3];
            o[q] = v;
        }
    }
}

// ---------------- Launch ----------------

extern "C" void kernel_launch(void* const* d_in, const int* in_sizes, int n_in,
                              void* d_out, int out_size, void* d_ws, size_t ws_size,
                              hipStream_t stream) {
    const float* in  = (const float*)d_in[0];
    const float* emb = (const float*)d_in[1];
    float* out = (float*)d_out;

    const size_t need = (size_t)8 * kSlab * sizeof(float);  // 128 MiB
    if (ws_size >= need) {
        float* scr = (float*)d_ws;
        dim3 gg(kGBlks), tb(kThr), gt(kBatch / 256u);
        hipLaunchKernelGGL(gather8, gg, tb, 0, stream, in, emb, scr, 0u);
        hipLaunchKernelGGL(transpose8, gt, tb, 0, stream, scr, out, 0u);
        hipLaunchKernelGGL(gather8, gg, tb, 0, stream, in, emb, scr, 8u);
        hipLaunchKernelGGL(transpose8, gt, tb, 0, stream, scr, out, 1u);
    } else {
        dim3 grid(kBatch / 256u), block(256u);
        hipLaunchKernelGGL(pyramid_fwd_mono, grid, block, 0, stream, in, emb, out);
    }
}

// Round 10
// 719.726 us; speedup vs baseline: 1.4289x; 1.4289x over previous
//
#include <hip/hip_runtime.h>
#include <stdint.h>

// PyramidGrid (instant-NGP hash grid, simplex interp) forward — R10.
//
// R9 post-mortem: free-running persistent blocks drifted out of level-phase ->
// multiple 4MB tables live in L2 at once -> FETCH 368MB->1.34GB, regression.
// Reverted to R8's dispatch-ordered phasing (lvl = blockIdx.x>>11).
// R10 deltas on R8: (1) input loads CACHED (were NT: every level paid ~900cyc
// HBM latency + 192MB of FETCH; now L3 serves re-reads ~450cyc) and hoisted to
// the block top behind a fence; (2) gathers split into two 8-load windows with
// separate fences -> consume A at vmcnt(8) while B stays in flight (no full
// drain). Scratch stores stay NT (full-line/wave, keeps L2 for the table).

constexpr uint32_t kBatch   = 1u << 21;
constexpr uint32_t kQuarter = kBatch / 4u;          // points per k-step in gather
constexpr size_t   kSlab    = (size_t)kBatch * 2u;  // floats per level slab

typedef float f32x2 __attribute__((ext_vector_type(2)));
typedef float f32x4 __attribute__((ext_vector_type(4)));

// cumulative row offsets (prev) and pow2 hash masks per level
constexpr uint32_t PREV[16] = {
    0u, 4096u, 36864u, 299008u, 823296u, 1347584u, 1871872u, 2396160u,
    2920448u, 3444736u, 3969024u, 4493312u, 5017600u, 5541888u, 6066176u, 6590464u};
constexpr uint32_t MASK[16] = {
    4095u, 32767u, 262143u, 524287u, 524287u, 524287u, 524287u, 524287u,
    524287u, 524287u, 524287u, 524287u, 524287u, 524287u, 524287u, 524287u};

// Shared per-point math (verified bit-exact vs reference in R1-R9).
__device__ __forceinline__ void corner_hashes_weights(
    float x0, float x1, float x2, float res, uint32_t mask, uint32_t prev,
    uint32_t& g0, uint32_t& g1, uint32_t& g2, uint32_t& g3,
    float& sa, float& sb, float& sc)
{
    const float fx0 = x0 * res;
    const float fx1 = x1 * res;
    const float fx2 = x2 * res;
    const int i0 = (int)fx0;            // trunc == floor (x >= 0)
    const int i1 = (int)fx1;
    const int i2 = (int)fx2;
    const float f0 = fx0 - (float)i0;   // exact fp32
    const float f1 = fx1 - (float)i1;
    const float f2 = fx2 - (float)i2;

    // stable ascending ranks (== inv_inds of stable argsort)
    const int r0 = (int)(f1 < f0) + (int)(f2 < f0);
    const int r1 = (int)(f0 < f1) + (int)(f2 < f1) + (int)(f0 == f1);
    const int r2 = (int)(f0 < f2) + (int)(f1 < f2) + (int)(f0 == f2) + (int)(f1 == f2);

    sa = fminf(fminf(f0, f1), f2);
    sc = fmaxf(fmaxf(f0, f1), f2);
    sb = __builtin_amdgcn_fmed3f(f0, f1, f2);

    // hash components (uint32 wrap multiply; PRIMES = {1, 2654435761, 805459861})
    const uint32_t A0 = (uint32_t)i0;
    const uint32_t A1 = A0 + 1u;
    const uint32_t B0 = (uint32_t)i1 * 2654435761u;
    const uint32_t B1 = ((uint32_t)i1 + 1u) * 2654435761u;
    const uint32_t C0 = (uint32_t)i2 * 805459861u;
    const uint32_t C1 = ((uint32_t)i2 + 1u) * 805459861u;

    const uint32_t h0 = A1 ^ B1 ^ C1;
    const uint32_t h1 = (r0 >= 1 ? A1 : A0) ^ (r1 >= 1 ? B1 : B0) ^ (r2 >= 1 ? C1 : C0);
    const uint32_t h2 = (r0 >= 2 ? A1 : A0) ^ (r1 >= 2 ? B1 : B0) ^ (r2 >= 2 ? C1 : C0);
    const uint32_t h3 = A0 ^ B0 ^ C0;

    g0 = (h0 & mask) + prev;
    g1 = (h1 & mask) + prev;
    g2 = (h2 & mask) + prev;
    g3 = (h3 & mask) + prev;
}

// ---------------- Fused per-level gather: 8 levels per launch ----------------
// blockIdx.x in [0, 8*2048): lvl = base + (bid >> 11). HW dispatches blocks in
// index order; one level's 2048 blocks ~= co-resident capacity, so levels run
// approximately serially -> the active level's <=4MB table stays L2-resident.

__global__ __launch_bounds__(256) void gather8(
    const float* __restrict__ in,    // [B,3]
    const float* __restrict__ emb,   // [7114752,2]
    float* __restrict__ scr,         // [8][B][2]
    uint32_t base)                   // 0 or 8
{
    const uint32_t bid  = blockIdx.x;
    const uint32_t lvl  = base + (bid >> 11);
    const uint32_t blk  = bid & 2047u;
    const uint32_t tid  = blk * 256u + threadIdx.x;

    const float res = (float)(16u << lvl);
    const uint32_t mask = MASK[lvl];
    const uint32_t prev = PREV[lvl];
    float* slab = scr + (size_t)(lvl - base) * kSlab;

    // Hoisted CACHED input loads for all 4 points (12 independent dword loads
    // in flight together; later levels hit L3/L2 instead of HBM).
    float xin[4][3];
#pragma unroll
    for (int k = 0; k < 4; ++k) {
        const uint32_t b = tid + (uint32_t)k * kQuarter;
        xin[k][0] = in[3u * b + 0u];
        xin[k][1] = in[3u * b + 1u];
        xin[k][2] = in[3u * b + 2u];
    }
    asm volatile(""
        : "+v"(xin[0][0]), "+v"(xin[0][1]), "+v"(xin[0][2]),
          "+v"(xin[1][0]), "+v"(xin[1][1]), "+v"(xin[1][2]),
          "+v"(xin[2][0]), "+v"(xin[2][1]), "+v"(xin[2][2]),
          "+v"(xin[3][0]), "+v"(xin[3][1]), "+v"(xin[3][2]));

    f32x2 e[4][4];
    float sa[4], sb[4], sc[4];

    // Window A: points 0,1 -> 8 gathers.
#pragma unroll
    for (int k = 0; k < 2; ++k) {
        uint32_t g0, g1, g2, g3;
        corner_hashes_weights(xin[k][0], xin[k][1], xin[k][2], res, mask, prev,
                              g0, g1, g2, g3, sa[k], sb[k], sc[k]);
        e[k][0] = *reinterpret_cast<const f32x2*>(emb + 2u * g0);
        e[k][1] = *reinterpret_cast<const f32x2*>(emb + 2u * g1);
        e[k][2] = *reinterpret_cast<const f32x2*>(emb + 2u * g2);
        e[k][3] = *reinterpret_cast<const f32x2*>(emb + 2u * g3);
    }
    // Window B: points 2,3 -> 8 gathers (issued before A is consumed).
#pragma unroll
    for (int k = 2; k < 4; ++k) {
        uint32_t g0, g1, g2, g3;
        corner_hashes_weights(xin[k][0], xin[k][1], xin[k][2], res, mask, prev,
                              g0, g1, g2, g3, sa[k], sb[k], sc[k]);
        e[k][0] = *reinterpret_cast<const f32x2*>(emb + 2u * g0);
        e[k][1] = *reinterpret_cast<const f32x2*>(emb + 2u * g1);
        e[k][2] = *reinterpret_cast<const f32x2*>(emb + 2u * g2);
        e[k][3] = *reinterpret_cast<const f32x2*>(emb + 2u * g3);
    }

    // Fence A only: compiler waits vmcnt(8) here — window B stays in flight
    // while A is combined/stored.
    asm volatile(""
        : "+v"(e[0][0]), "+v"(e[0][1]), "+v"(e[0][2]), "+v"(e[0][3]),
          "+v"(e[1][0]), "+v"(e[1][1]), "+v"(e[1][2]), "+v"(e[1][3]));

#pragma unroll
    for (int k = 0; k < 2; ++k) {
        const float w0 = sa[k];
        const float w1 = sb[k] - sa[k];
        const float w2 = sc[k] - sb[k];
        const float w3 = 1.0f - sc[k];
        f32x2 v;
        v.x = w0 * e[k][0].x + w1 * e[k][1].x + w2 * e[k][2].x + w3 * e[k][3].x;
        v.y = w0 * e[k][0].y + w1 * e[k][1].y + w2 * e[k][2].y + w3 * e[k][3].y;
        const uint32_t b = tid + (uint32_t)k * kQuarter;
        __builtin_nontemporal_store(v, reinterpret_cast<f32x2*>(slab + 2u * (size_t)b));
    }

    // Fence B, then combine/store.
    asm volatile(""
        : "+v"(e[2][0]), "+v"(e[2][1]), "+v"(e[2][2]), "+v"(e[2][3]),
          "+v"(e[3][0]), "+v"(e[3][1]), "+v"(e[3][2]), "+v"(e[3][3]));

#pragma unroll
    for (int k = 2; k < 4; ++k) {
        const float w0 = sa[k];
        const float w1 = sb[k] - sa[k];
        const float w2 = sc[k] - sb[k];
        const float w3 = 1.0f - sc[k];
        f32x2 v;
        v.x = w0 * e[k][0].x + w1 * e[k][1].x + w2 * e[k][2].x + w3 * e[k][3].x;
        v.y = w0 * e[k][0].y + w1 * e[k][1].y + w2 * e[k][2].y + w3 * e[k][3].y;
        const uint32_t b = tid + (uint32_t)k * kQuarter;
        __builtin_nontemporal_store(v, reinterpret_cast<f32x2*>(slab + 2u * (size_t)b));
    }
}

// Assemble 8 level slabs -> contiguous 64B (one full line) per point.
__global__ __launch_bounds__(256) void transpose8(
    const float* __restrict__ scr,   // [8][B][2]
    float* __restrict__ out,         // [B,32]
    uint32_t half)                   // 0: levels 0-7, 1: levels 8-15
{
    const uint32_t b = blockIdx.x * 256u + threadIdx.x;
    float v[16];
#pragma unroll
    for (int l = 0; l < 8; ++l) {
        const f32x2 e = __builtin_nontemporal_load(
            reinterpret_cast<const f32x2*>(scr + (size_t)l * kSlab + 2u * (size_t)b));
        v[2 * l + 0] = e.x;
        v[2 * l + 1] = e.y;
    }
    float* o = out + (size_t)b * 32u + (size_t)half * 16u;
#pragma unroll
    for (int q = 0; q < 4; ++q) {
        f32x4 t;
        t.x = v[4 * q + 0];
        t.y = v[4 * q + 1];
        t.z = v[4 * q + 2];
        t.w = v[4 * q + 3];
        *reinterpret_cast<f32x4*>(o + 4 * q) = t;
    }
}

// ---------------- Fallback: monolithic (if ws too small) ----------------

__global__ __launch_bounds__(256) void pyramid_fwd_mono(
    const float* __restrict__ in,
    const float* __restrict__ emb,
    float* __restrict__ out)
{
    const uint32_t b = blockIdx.x * 256u + threadIdx.x;
    const float x0 = in[3u * b + 0u];
    const float x1 = in[3u * b + 1u];
    const float x2 = in[3u * b + 2u];

#pragma unroll
    for (int g = 0; g < 2; ++g) {
        float o8[16];
#pragma unroll
        for (int k = 0; k < 8; ++k) {
            const int lvl = g * 8 + k;
            const float res = (float)(16 << lvl);
            uint32_t g0, g1, g2, g3;
            float sa, sb, sc;
            corner_hashes_weights(x0, x1, x2, res, MASK[lvl], PREV[lvl],
                                  g0, g1, g2, g3, sa, sb, sc);
            const f32x2 e0 = *reinterpret_cast<const f32x2*>(emb + 2u * g0);
            const f32x2 e1 = *reinterpret_cast<const f32x2*>(emb + 2u * g1);
            const f32x2 e2 = *reinterpret_cast<const f32x2*>(emb + 2u * g2);
            const f32x2 e3 = *reinterpret_cast<const f32x2*>(emb + 2u * g3);
            const float w0 = sa, w1 = sb - sa, w2 = sc - sb, w3 = 1.0f - sc;
            o8[2 * k + 0] = w0 * e0.x + w1 * e1.x + w2 * e2.x + w3 * e3.x;
            o8[2 * k + 1] = w0 * e0.y + w1 * e1.y + w2 * e2.y + w3 * e3.y;
        }
        f32x4* o = reinterpret_cast<f32x4*>(out + (size_t)b * 32u + (size_t)g * 16u);
#pragma unroll
        for (int q = 0; q < 4; ++q) {
            f32x4 v;
            v.x = o8[4 * q + 0];
            v.y = o8[4 * q + 1];
            v.z = o8[4 * q + 2];
            v.w = o8[4 * q + 3];
            o[q] = v;
        }
    }
}

// ---------------- Launch ----------------

extern "C" void kernel_launch(void* const* d_in, const int* in_sizes, int n_in,
                              void* d_out, int out_size, void* d_ws, size_t ws_size,
                              hipStream_t stream) {
    const float* in  = (const float*)d_in[0];
    const float* emb = (const float*)d_in[1];
    float* out = (float*)d_out;

    const size_t need = (size_t)8 * kSlab * sizeof(float);  // 128 MiB
    if (ws_size >= need) {
        float* scr = (float*)d_ws;
        dim3 gg(8u * 2048u), tb(256u), gt(kBatch / 256u);
        hipLaunchKernelGGL(gather8, gg, tb, 0, stream, in, emb, scr, 0u);
        hipLaunchKernelGGL(transpose8, gt, tb, 0, stream, scr, out, 0u);
        hipLaunchKernelGGL(gather8, gg, tb, 0, stream, in, emb, scr, 8u);
        hipLaunchKernelGGL(transpose8, gt, tb, 0, stream, scr, out, 1u);
    } else {
        dim3 grid(kBatch / 256u), block(256u);
        hipLaunchKernelGGL(pyramid_fwd_mono, grid, block, 0, stream, in, emb, out);
    }
}